// Round 9
// baseline (76.855 us; speedup 1.0000x reference)
//
#include <hip/hip_runtime.h>
#include <hip/hip_bf16.h>

typedef __attribute__((ext_vector_type(8))) short short8;
typedef __attribute__((ext_vector_type(4))) float f32x4;

static constexpr int S_ = 256;
static constexpr int D_ = 64;
static constexpr int QB = 4;          // queries per block (1 per wave)
static constexpr int JS = 4;          // j-split across blocks
static constexpr int JH = S_ / JS;    // 64 j rows per block
// softmax scale * log2(e): scores come out of the GEMM in log2 domain
static constexpr float QSCALE = 0.125f * 1.44269504088896340736f;
static constexpr int NBLK = 8 * (S_ / QB) * JS;          // 2048
static constexpr int WS_O_CNT = NBLK * QB * D_;          // 524288 partial-O floats

__device__ __forceinline__ unsigned cvt_pk_bf16(float lo, float hi) {
    unsigned r;
    asm("v_cvt_pk_bf16_f32 %0, %1, %2" : "=v"(r) : "v"(lo), "v"(hi));
    return r;
}

__global__ __launch_bounds__(256, 2) void tritt_part(
    const float* __restrict__ qg, const float* __restrict__ k1g,
    const float* __restrict__ k2g, const float* __restrict__ v1g,
    const float* __restrict__ v2g, float* __restrict__ ws)
{
    __shared__ unsigned short sK2[JH * D_];   // own j-quarter, bf16 swizzled (8 KB)
    __shared__ float sPi[QB][S_];             // 4 KB, wave-local strips (full i)
    __shared__ float sPj[QB][JH];             // 1 KB (own j-quarter)
    __shared__ float sTmp[4][QB * D_];        // 4 KB, O partials
    __shared__ float sL[QB];
    // total ~17.3 KB

    const int tid = threadIdx.x;
    const int bid = blockIdx.x;
    const int js = bid & 3;
    const int qt = (bid >> 2) & 63;
    const int h  = bid >> 8;
    const int j0 = js * JH;
    const int q0 = qt * QB;

    const float* K1h = k1g + h * (S_ * D_);
    const float* K2h = k2g + h * (S_ * D_);

    // ---- stage own K2 quarter as swizzled bf16 ----
    #pragma unroll
    for (int it = 0; it < 4; ++it) {
        const int e4   = tid * 4 + it * 1024;         // < 4096
        const int lrow = e4 >> 6, d = e4 & 63;
        const int idx  = lrow * 64 + (d ^ ((lrow & 7) << 3));
        const float4 b = *(const float4*)(K2h + j0 * 64 + e4);
        uint2 pb; pb.x = cvt_pk_bf16(b.x, b.y); pb.y = cvt_pk_bf16(b.z, b.w);
        *(uint2*)&sK2[idx] = pb;
    }

    const int w   = tid >> 6;    // wave id == query index within tile
    const int l   = tid & 63;
    const int g   = l >> 4;      // 16-lane group (k-slice g*8..g*8+7)
    const int sub = l & 15;

    // Q fragment for this wave's query, straight from global (pre-scaled)
    float qs[2][8];
    {
        const float* Qrow = qg + (h * S_ + q0 + w) * D_;
        #pragma unroll
        for (int k = 0; k < 2; ++k) {
            const f32x4 a = *(const f32x4*)(Qrow + k * 32 + g * 8);
            const f32x4 b = *(const f32x4*)(Qrow + k * 32 + g * 8 + 4);
            qs[k][0]=a[0]*QSCALE; qs[k][1]=a[1]*QSCALE; qs[k][2]=a[2]*QSCALE; qs[k][3]=a[3]*QSCALE;
            qs[k][4]=b[0]*QSCALE; qs[k][5]=b[1]*QSCALE; qs[k][6]=b[2]*QSCALE; qs[k][7]=b[3]*QSCALE;
        }
    }
    __syncthreads();

    float pjreg[4];
    #pragma unroll
    for (int a = 0; a < 4; ++a) pjreg[a] = 0.f;

    // ---- 8 passes of 2 i-tiles over full i; j runs over own quarter (64) ----
    for (int pass = 0; pass < 8; ++pass) {
        // A fragments for 2 i-tiles: W[i,d] = K1[i,d]*Qs[d] from GLOBAL K1
        short8 af[2][2];
        #pragma unroll
        for (int t = 0; t < 2; ++t) {
            const int arow = pass * 32 + t * 16 + sub;
            #pragma unroll
            for (int k = 0; k < 2; ++k) {
                const f32x4 a = *(const f32x4*)(K1h + arow * 64 + k * 32 + g * 8);
                const f32x4 b = *(const f32x4*)(K1h + arow * 64 + k * 32 + g * 8 + 4);
                union { unsigned u[4]; short8 s; } pk;
                pk.u[0] = cvt_pk_bf16(a[0] * qs[k][0], a[1] * qs[k][1]);
                pk.u[1] = cvt_pk_bf16(a[2] * qs[k][2], a[3] * qs[k][3]);
                pk.u[2] = cvt_pk_bf16(b[0] * qs[k][4], b[1] * qs[k][5]);
                pk.u[3] = cvt_pk_bf16(b[2] * qs[k][6], b[3] * qs[k][7]);
                af[t][k] = pk.s;
            }
        }

        float pireg[2][4];
        #pragma unroll
        for (int t = 0; t < 2; ++t)
            #pragma unroll
            for (int r = 0; r < 4; ++r) pireg[t][r] = 0.f;

        #pragma unroll
        for (int jt = 0; jt < 4; ++jt) {          // own j-quarter: 4 tiles of 16
            const int jrow = jt * 16 + sub;       // local row in sK2
            const int jsw  = (jrow & 7) << 3;
            const short8 b0 = *(const short8*)&sK2[jrow * 64 + ((g * 8) ^ jsw)];
            const short8 b1 = *(const short8*)&sK2[jrow * 64 + ((32 + g * 8) ^ jsw)];
            f32x4 acc0 = __builtin_amdgcn_mfma_f32_16x16x32_bf16(af[0][0], b0, (f32x4){0.f,0.f,0.f,0.f}, 0, 0, 0);
            f32x4 acc1 = __builtin_amdgcn_mfma_f32_16x16x32_bf16(af[1][0], b0, (f32x4){0.f,0.f,0.f,0.f}, 0, 0, 0);
            acc0 = __builtin_amdgcn_mfma_f32_16x16x32_bf16(af[0][1], b1, acc0, 0, 0, 0);
            acc1 = __builtin_amdgcn_mfma_f32_16x16x32_bf16(af[1][1], b1, acc1, 0, 0, 0);
            // p = 2^t ; pi independent adds, pj 2-level tree
            float e0[4], e1[4];
            #pragma unroll
            for (int r = 0; r < 4; ++r) {
                e0[r] = __builtin_amdgcn_exp2f(acc0[r]);
                e1[r] = __builtin_amdgcn_exp2f(acc1[r]);
                pireg[0][r] += e0[r];    // i = pass*32 + 0*16 + g*4 + r
                pireg[1][r] += e1[r];    // i = pass*32 + 1*16 + g*4 + r
            }
            const float s0 = (e0[0] + e0[1]) + (e0[2] + e0[3]);
            const float s1 = (e1[0] + e1[1]) + (e1[2] + e1[3]);
            pjreg[jt] += s0 + s1;        // j(local) = jt*16 + sub
        }

        // flush pi for these 32 i's (reduce over the 16 sub lanes = distinct j)
        #pragma unroll
        for (int t = 0; t < 2; ++t)
            #pragma unroll
            for (int r = 0; r < 4; ++r) {
                float v = pireg[t][r];
                v += __shfl_xor(v, 1); v += __shfl_xor(v, 2);
                v += __shfl_xor(v, 4); v += __shfl_xor(v, 8);
                if (sub == 0) sPi[w][pass * 32 + t * 16 + g * 4 + r] = v;
            }
    }

    // pj: reduce over the 4 groups (distinct i) -> wave-local strip
    #pragma unroll
    for (int jj = 0; jj < 4; ++jj) {
        float v = pjreg[jj];
        v += __shfl_xor(v, 16); v += __shfl_xor(v, 32);
        if (l < 16) sPj[w][jj * 16 + l] = v;
    }

    // partial l = sum_i pi (this block's j-quarter contribution), wave-local
    {
        float ls = sPi[w][l] + sPi[w][64 + l] + sPi[w][128 + l] + sPi[w][192 + l];
        ls += __shfl_xor(ls, 1);  ls += __shfl_xor(ls, 2);  ls += __shfl_xor(ls, 4);
        ls += __shfl_xor(ls, 8);  ls += __shfl_xor(ls, 16); ls += __shfl_xor(ls, 32);
        if (l == 0) sL[w] = ls;
    }
    __syncthreads();

    // ---- cooperative O partials ----
    // wave w: V1 rows [w*64, w*64+64) (full i) + V2-quarter rows [w*16, w*16+16)
    {
        const int d = l;
        const float* V1h = v1g + h * (S_ * D_);
        const float* V2h = v2g + h * (S_ * D_);
        float p0 = 0.f, p1 = 0.f, p2 = 0.f, p3 = 0.f;
        #pragma unroll 4
        for (int rb = 0; rb < 16; ++rb) {          // V1: 64 rows
            const int r0 = w * 64 + rb * 4;
            f32x4 pi0 = *(const f32x4*)&sPi[0][r0];
            f32x4 pi1 = *(const f32x4*)&sPi[1][r0];
            f32x4 pi2 = *(const f32x4*)&sPi[2][r0];
            f32x4 pi3 = *(const f32x4*)&sPi[3][r0];
            #pragma unroll
            for (int e = 0; e < 4; ++e) {
                const float v1 = V1h[(r0 + e) * D_ + d];
                p0 += pi0[e] * v1; p1 += pi1[e] * v1;
                p2 += pi2[e] * v1; p3 += pi3[e] * v1;
            }
        }
        #pragma unroll
        for (int rb = 0; rb < 4; ++rb) {           // V2 own quarter: 16 rows
            const int r0 = w * 16 + rb * 4;        // local row
            f32x4 pj0 = *(const f32x4*)&sPj[0][r0];
            f32x4 pj1 = *(const f32x4*)&sPj[1][r0];
            f32x4 pj2 = *(const f32x4*)&sPj[2][r0];
            f32x4 pj3 = *(const f32x4*)&sPj[3][r0];
            #pragma unroll
            for (int e = 0; e < 4; ++e) {
                const float v2 = V2h[(j0 + r0 + e) * D_ + d];
                p0 += pj0[e] * v2; p1 += pj1[e] * v2;
                p2 += pj2[e] * v2; p3 += pj3[e] * v2;
            }
        }
        sTmp[w][0 * 64 + d] = p0; sTmp[w][1 * 64 + d] = p1;
        sTmp[w][2 * 64 + d] = p2; sTmp[w][3 * 64 + d] = p3;
    }
    __syncthreads();
    {
        const int q = tid >> 6, d = tid & 63;
        const float oo = sTmp[0][q * 64 + d] + sTmp[1][q * 64 + d]
                       + sTmp[2][q * 64 + d] + sTmp[3][q * 64 + d];
        ws[(bid * QB + q) * D_ + d] = oo;
        if (tid < QB) ws[WS_O_CNT + bid * QB + tid] = sL[tid];
    }
}

__global__ __launch_bounds__(256) void tritt_combine(
    const float* __restrict__ ws, float* __restrict__ outg)
{
    const int flat = blockIdx.x * 256 + threadIdx.x;
    const int d  = flat & 63;
    const int q  = (flat >> 6) & 3;
    const int qt = (flat >> 8) & 63;
    const int h  = flat >> 14;
    const int bid0 = (h * 64 + qt) * JS;       // js = 0
    float oo = 0.f, lsum = 0.f;
    #pragma unroll
    for (int js = 0; js < JS; ++js) {
        const int ii = (bid0 + js) * QB + q;
        oo   += ws[ii * D_ + d];
        lsum += ws[WS_O_CNT + ii];
    }
    outg[(h * S_ + qt * QB + q) * D_ + d] = oo / lsum;
    if (d == 0)
        outg[8 * S_ * D_ + h * S_ + qt * QB + q] = logf(lsum);
}

extern "C" void kernel_launch(void* const* d_in, const int* in_sizes, int n_in,
                              void* d_out, int out_size, void* d_ws, size_t ws_size,
                              hipStream_t stream) {
    const float* q  = (const float*)d_in[0];
    const float* k1 = (const float*)d_in[1];
    const float* k2 = (const float*)d_in[2];
    const float* v1 = (const float*)d_in[3];
    const float* v2 = (const float*)d_in[4];
    float* out = (float*)d_out;
    float* ws  = (float*)d_ws;
    tritt_part<<<dim3(NBLK), dim3(256), 0, stream>>>(q, k1, k2, v1, v2, ws);
    tritt_combine<<<dim3((8 * S_ * D_) / 256), dim3(256), 0, stream>>>(ws, out);
}

// Round 10
// 49.225 us; speedup vs baseline: 1.5613x; 1.5613x over previous
//
#include <hip/hip_runtime.h>
#include <hip/hip_bf16.h>

typedef __attribute__((ext_vector_type(8))) short short8;
typedef __attribute__((ext_vector_type(4))) float f32x4;

static constexpr int S_ = 256;
static constexpr int D_ = 64;
// softmax scale * log2(e): GEMM directly produces log2-domain scores
static constexpr float QSCALE = 0.125f * 1.44269504088896340736f;

__device__ __forceinline__ unsigned cvt_pk_bf16(float lo, float hi) {
    unsigned r;
    asm("v_cvt_pk_bf16_f32 %0, %1, %2" : "=v"(r) : "v"(lo), "v"(hi));
    return r;
}

// 256 threads = 4 waves = 2 queries x 2 i-halves. Full j per wave.
// LDS ~38.9 KB -> 4 blocks/CU = 16 waves/CU. Single kernel, no duplication.
__global__ __launch_bounds__(256, 2) void tritt_fused(
    const float* __restrict__ qg, const float* __restrict__ k1g,
    const float* __restrict__ k2g, const float* __restrict__ v1g,
    const float* __restrict__ v2g, float* __restrict__ outg)
{
    __shared__ unsigned short sK2[S_ * D_];  // 32 KB, bf16 XOR-swizzled
    __shared__ float sPi[2][S_];             // 2 KB  (per-query pi, both halves)
    __shared__ float sPjH[4][S_];            // 4 KB  (per-wave pj partials)

    const int tid = threadIdx.x;
    const int qt = blockIdx.x & 127;         // 128 q-tiles of 2
    const int h  = blockIdx.x >> 7;
    const int q0 = qt * 2;

    const float* K1h = k1g + h * (S_ * D_);
    const float* K2h = k2g + h * (S_ * D_);

    // ---- stage K2 (full) as swizzled bf16 ----
    #pragma unroll
    for (int it = 0; it < 16; ++it) {
        const int e4  = tid * 4 + it * 1024;
        const int row = e4 >> 6, d = e4 & 63;
        const int idx = row * 64 + (d ^ ((row & 7) << 3));
        const float4 b = *(const float4*)(K2h + e4);
        uint2 pb; pb.x = cvt_pk_bf16(b.x, b.y); pb.y = cvt_pk_bf16(b.z, b.w);
        *(uint2*)&sK2[idx] = pb;
    }

    const int w     = tid >> 6;
    const int l     = tid & 63;
    const int g     = l >> 4;      // 16-lane group (k-slice g*8..g*8+7)
    const int sub   = l & 15;
    const int q     = w & 1;       // query within tile
    const int ihalf = w >> 1;      // i-half this wave owns
    const int ibase0 = ihalf * 128;

    // Q fragment for this wave's query, from global (pre-scaled)
    float qs[2][8];
    {
        const float* Qrow = qg + (h * S_ + q0 + q) * D_;
        #pragma unroll
        for (int k = 0; k < 2; ++k) {
            const f32x4 a = *(const f32x4*)(Qrow + k * 32 + g * 8);
            const f32x4 b = *(const f32x4*)(Qrow + k * 32 + g * 8 + 4);
            qs[k][0]=a[0]*QSCALE; qs[k][1]=a[1]*QSCALE; qs[k][2]=a[2]*QSCALE; qs[k][3]=a[3]*QSCALE;
            qs[k][4]=b[0]*QSCALE; qs[k][5]=b[1]*QSCALE; qs[k][6]=b[2]*QSCALE; qs[k][7]=b[3]*QSCALE;
        }
    }
    __syncthreads();

    float pjreg[16];
    #pragma unroll
    for (int a = 0; a < 16; ++a) pjreg[a] = 0.f;

    // ---- 4 passes of 2 i-tiles (own 128-row i-half) x full j (256) ----
    for (int pass = 0; pass < 4; ++pass) {
        // A fragments: W[i,d] = K1[i,d]*Qs[d] from GLOBAL K1
        short8 af[2][2];
        #pragma unroll
        for (int t = 0; t < 2; ++t) {
            const int arow = ibase0 + pass * 32 + t * 16 + sub;
            #pragma unroll
            for (int k = 0; k < 2; ++k) {
                const f32x4 a = *(const f32x4*)(K1h + arow * 64 + k * 32 + g * 8);
                const f32x4 b = *(const f32x4*)(K1h + arow * 64 + k * 32 + g * 8 + 4);
                union { unsigned u[4]; short8 s; } pk;
                pk.u[0] = cvt_pk_bf16(a[0] * qs[k][0], a[1] * qs[k][1]);
                pk.u[1] = cvt_pk_bf16(a[2] * qs[k][2], a[3] * qs[k][3]);
                pk.u[2] = cvt_pk_bf16(b[0] * qs[k][4], b[1] * qs[k][5]);
                pk.u[3] = cvt_pk_bf16(b[2] * qs[k][6], b[3] * qs[k][7]);
                af[t][k] = pk.s;
            }
        }

        float pireg[2][4];
        #pragma unroll
        for (int t = 0; t < 2; ++t)
            #pragma unroll
            for (int r = 0; r < 4; ++r) pireg[t][r] = 0.f;

        #pragma unroll
        for (int jc = 0; jc < 4; ++jc) {
            #pragma unroll
            for (int jt = 0; jt < 4; ++jt) {
                const int jrow = jc * 64 + jt * 16 + sub;
                const int jsw  = (jrow & 7) << 3;
                const short8 b0 = *(const short8*)&sK2[jrow * 64 + ((g * 8) ^ jsw)];
                const short8 b1 = *(const short8*)&sK2[jrow * 64 + ((32 + g * 8) ^ jsw)];
                f32x4 acc0 = __builtin_amdgcn_mfma_f32_16x16x32_bf16(af[0][0], b0, (f32x4){0.f,0.f,0.f,0.f}, 0, 0, 0);
                f32x4 acc1 = __builtin_amdgcn_mfma_f32_16x16x32_bf16(af[1][0], b0, (f32x4){0.f,0.f,0.f,0.f}, 0, 0, 0);
                acc0 = __builtin_amdgcn_mfma_f32_16x16x32_bf16(af[0][1], b1, acc0, 0, 0, 0);
                acc1 = __builtin_amdgcn_mfma_f32_16x16x32_bf16(af[1][1], b1, acc1, 0, 0, 0);
                float e0[4], e1[4];
                #pragma unroll
                for (int r = 0; r < 4; ++r) {
                    e0[r] = __builtin_amdgcn_exp2f(acc0[r]);
                    e1[r] = __builtin_amdgcn_exp2f(acc1[r]);
                    pireg[0][r] += e0[r];   // i = ibase0 + pass*32 + 0*16 + g*4 + r
                    pireg[1][r] += e1[r];
                }
                const float s0 = (e0[0] + e0[1]) + (e0[2] + e0[3]);
                const float s1 = (e1[0] + e1[1]) + (e1[2] + e1[3]);
                pjreg[jc * 4 + jt] += s0 + s1;   // j = (jc*4+jt)*16 + sub
            }
        }

        // flush pi (reduce over 16 sub lanes = distinct j)
        #pragma unroll
        for (int t = 0; t < 2; ++t)
            #pragma unroll
            for (int r = 0; r < 4; ++r) {
                float v = pireg[t][r];
                v += __shfl_xor(v, 1); v += __shfl_xor(v, 2);
                v += __shfl_xor(v, 4); v += __shfl_xor(v, 8);
                if (sub == 0) sPi[q][ibase0 + pass * 32 + t * 16 + g * 4 + r] = v;
            }
    }

    // pj partials: reduce over the 4 groups (distinct i) -> per-wave strip
    #pragma unroll
    for (int jj = 0; jj < 16; ++jj) {
        float v = pjreg[jj];
        v += __shfl_xor(v, 16); v += __shfl_xor(v, 32);
        if (l < 16) sPjH[w][jj * 16 + l] = v;
    }
    __syncthreads();   // main phase done; sK2 now dead

    // ---- cooperative epilogue: wave w covers rows [w*64, w*64+64) for both q ----
    float* sTmp = (float*)sK2;   // 512 floats carved from dead sK2
    {
        const int d = l;
        const float* V1h = v1g + h * (S_ * D_);
        const float* V2h = v2g + h * (S_ * D_);
        float p0 = 0.f, p1 = 0.f;
        #pragma unroll 4
        for (int rb = 0; rb < 16; ++rb) {
            const int r0 = w * 64 + rb * 4;
            const f32x4 pi0 = *(const f32x4*)&sPi[0][r0];
            const f32x4 pi1 = *(const f32x4*)&sPi[1][r0];
            const f32x4 pa0 = *(const f32x4*)&sPjH[0][r0];
            const f32x4 pa1 = *(const f32x4*)&sPjH[1][r0];
            const f32x4 pa2 = *(const f32x4*)&sPjH[2][r0];
            const f32x4 pa3 = *(const f32x4*)&sPjH[3][r0];
            #pragma unroll
            for (int e = 0; e < 4; ++e) {
                const float v1 = V1h[(r0 + e) * D_ + d];
                const float v2 = V2h[(r0 + e) * D_ + d];
                p0 += pi0[e] * v1 + (pa0[e] + pa2[e]) * v2;
                p1 += pi1[e] * v1 + (pa1[e] + pa3[e]) * v2;
            }
        }
        sTmp[w * 128 + 0 * 64 + d] = p0;
        sTmp[w * 128 + 1 * 64 + d] = p1;
    }
    __syncthreads();
    if (tid < 128) {
        const int qq = tid >> 6, d = tid & 63;
        const float oo = sTmp[0 * 128 + qq * 64 + d] + sTmp[1 * 128 + qq * 64 + d]
                       + sTmp[2 * 128 + qq * 64 + d] + sTmp[3 * 128 + qq * 64 + d];
        float ls = sPi[qq][d] + sPi[qq][64 + d] + sPi[qq][128 + d] + sPi[qq][192 + d];
        ls += __shfl_xor(ls, 1);  ls += __shfl_xor(ls, 2);  ls += __shfl_xor(ls, 4);
        ls += __shfl_xor(ls, 8);  ls += __shfl_xor(ls, 16); ls += __shfl_xor(ls, 32);
        outg[(h * S_ + q0 + qq) * D_ + d] = oo / ls;
        if (d == 0)
            outg[8 * S_ * D_ + h * S_ + q0 + qq] = logf(ls);
    }
}

extern "C" void kernel_launch(void* const* d_in, const int* in_sizes, int n_in,
                              void* d_out, int out_size, void* d_ws, size_t ws_size,
                              hipStream_t stream) {
    const float* q  = (const float*)d_in[0];
    const float* k1 = (const float*)d_in[1];
    const float* k2 = (const float*)d_in[2];
    const float* v1 = (const float*)d_in[3];
    const float* v2 = (const float*)d_in[4];
    float* out = (float*)d_out;
    tritt_fused<<<dim3(8 * (S_ / 2)), dim3(256), 0, stream>>>(q, k1, k2, v1, v2, out);
}